// Round 16
// baseline (56.041 us; speedup 1.0000x reference)
//
#include <hip/hip_runtime.h>

// Depthwise xcorr: out[p][oy][ox] = sum_{ky,kx} x[p][oy+ky][ox+kx] * z[p][ky][kx]
// 32768 planes. x: 31x31, z: 7x7, out: 25x25, fp32.
//
// Round 16: full-row compute threads + ds_read_b128.
// R15 post-mortem: 45.5us timed but all pipes <40% - FMA stream stalled on
// 170 scalar ds_reads/thread. Now thread = (plane, output row oy), acc[25]:
// per ky it loads the whole 32-dword input row as 8 x float4 (ds_read_b128,
// 16B-aligned: idx = (cpp<<10)|(row<<5)|4*(c^rf)) then runs 175 FMAs.
// LDS ops/thread 170 -> 105; XOR swizzle spreads lane-rows mod 8 over all
// banks -> b128 at its natural ~12cyc, no conflict blowup. Staging/layout/
// grid identical to R15 (proven: absmax 0.125).

#define PPB 5
#define WX 31
#define XPLANE 961
#define TDW (PPB * XPLANE)      // 4805 x dwords per tile
#define LPLANE 1024             // 32 rows x 32 cols (row 31 / col 31 = pad)
#define XREG (PPB * LPLANE)     // 5120 dwords
#define ZPLANE 49
#define ZDW (PPB * ZPLANE)      // 245
#define ZREG 256
#define OPLANE 625
#define WO 25

typedef __attribute__((address_space(1))) const void gaddr_t;
typedef __attribute__((address_space(3))) void laddr_t;

__global__ __launch_bounds__(128, 2) void dwxcorr_kernel(
    const float* __restrict__ z, const float* __restrict__ x,
    float* __restrict__ out, int nplanes) {
  __shared__ float lds[XREG + ZREG];  // 21504 B -> 7 blocks/CU

  const int tid = threadIdx.x;
  const int t = blockIdx.x;
  const int wb4 = (tid & ~63) * 4;    // wave-uniform dword base, 16B/lane
  const int wb1 = tid & ~63;          // wave-uniform dword base, 4B/lane
  const long XTOT = (long)nplanes * XPLANE;
  const long ZTOT = (long)nplanes * ZPLANE;
  const long xoff = (long)t * TDW;
  const long zoff = (long)t * ZDW;
  const long gz0 = zoff & ~3L;
  const int offz = (int)(zoff & 3);

  // LDS dword (p, row, c) holds x[p*961 + row*31 + (c ^ ((row&7)<<2))]
  if (xoff + TDW + 31 <= XTOT && gz0 + ZREG <= ZTOT) {
    // ---- fast path: 10 passes of 16B chunks, source pre-swizzled ----
#pragma unroll
    for (int c = 0; c < 10; ++c) {
      int s = c * 512 + tid * 4;       // 4-aligned LDS dword slot
      int p = s >> 10;
      int row = (s >> 5) & 31;         // 31 = pad row (dup, never read)
      int q = s & 31;                  // 4-aligned chunk col
      int qq = q ^ ((row & 7) << 2);   // still 4-aligned, <= 28
      long g = xoff + p * XPLANE + row * WX + qq;
      __builtin_amdgcn_global_load_lds((gaddr_t*)(x + g),
                                       (laddr_t*)&lds[c * 512 + wb4], 16, 0, 0);
    }
    if (tid < 63)                      // z: 252 dwords, linear
      __builtin_amdgcn_global_load_lds((gaddr_t*)(z + gz0 + tid * 4),
                                       (laddr_t*)&lds[XREG + wb4], 16, 0, 0);
  } else {
    // ---- tail tile (1 of 6554): 4B staging, everything clamped ----
#pragma unroll
    for (int c = 0; c < 40; ++c) {
      int s = c * 128 + tid;
      int p = s >> 10;
      int row = (s >> 5) & 31;
      int q = s & 31;
      int qq = q ^ ((row & 7) << 2);
      long g = xoff + p * XPLANE + row * WX + qq;
      if (g > XTOT - 1) g = XTOT - 1;  // dup, never read
      __builtin_amdgcn_global_load_lds((gaddr_t*)(x + g),
                                       (laddr_t*)&lds[c * 128 + wb1], 4, 0, 0);
    }
    if (tid < 63) {
      long gz = gz0 + tid * 4;
      if (gz > ZTOT - 4) gz = ZTOT - 4;
      __builtin_amdgcn_global_load_lds((gaddr_t*)(z + gz),
                                       (laddr_t*)&lds[XREG + wb4], 16, 0, 0);
    }
  }
  __syncthreads();  // single drain + barrier

  // ---- compute: thread -> (plane cpp, output row oy); 125/128 active ----
  const int p0 = t * PPB;
  const int pmax = min(PPB, nplanes - p0);
  const int cpp = tid / 25;
  if (tid >= PPB * 25 || cpp >= pmax) return;
  const int oy = tid - cpp * 25;       // output row 0..24

  const float* zb = &lds[XREG + offz + cpp * ZPLANE];  // broadcast b32 reads

  float acc[25];
#pragma unroll
  for (int j = 0; j < 25; ++j) acc[j] = 0.0f;

#pragma unroll
  for (int ky = 0; ky < 7; ++ky) {
    const int row = oy + ky;           // input row 0..30
    const int rf = row & 7;
    const float4* rp = (const float4*)&lds[(cpp << 10) | (row << 5)];
    float rowbuf[32];
#pragma unroll
    for (int c = 0; c < 8; ++c) {
      float4 v = rp[c ^ rf];           // LDS chunk (c^rf) holds x chunk c
      rowbuf[c * 4 + 0] = v.x;
      rowbuf[c * 4 + 1] = v.y;
      rowbuf[c * 4 + 2] = v.z;
      rowbuf[c * 4 + 3] = v.w;
    }
#pragma unroll
    for (int kx = 0; kx < 7; ++kx) {
      const float zv = zb[ky * 7 + kx];
#pragma unroll
      for (int ox = 0; ox < 25; ++ox)
        acc[ox] = fmaf(rowbuf[ox + kx], zv, acc[ox]);
    }
  }

  // ---- write the output row (25 contiguous dwords) ----
  float* ob = out + (long)(p0 + cpp) * OPLANE + oy * WO;
#pragma unroll
  for (int j = 0; j < 25; ++j) ob[j] = acc[j];
}

extern "C" void kernel_launch(void* const* d_in, const int* in_sizes, int n_in,
                              void* d_out, int out_size, void* d_ws, size_t ws_size,
                              hipStream_t stream) {
  const float* z = (const float*)d_in[0];  // [B,C,7,7]
  const float* x = (const float*)d_in[1];  // [B,C,31,31]
  float* out = (float*)d_out;              // [B,C,25,25]

  const int nplanes = in_sizes[0] / ZPLANE;      // 32768
  const int blocks = (nplanes + PPB - 1) / PPB;  // 6554

  hipLaunchKernelGGL(dwxcorr_kernel, dim3(blocks), dim3(128), 0, stream,
                     z, x, out, nplanes);
}